// Round 10
// baseline (205.409 us; speedup 1.0000x reference)
//
#include <hip/hip_runtime.h>
#include <hip/hip_bf16.h>
#include <math.h>

#define NP 10
#define NE 45
#define TS 16                      // timesteps per block
#define EPB (TS * NE)              // 720 edges per block
#define BLOCK 256
#define NCHUNK ((EPB + 63) / 64)   // 12 chunks of 64 edge-slots

typedef __attribute__((ext_vector_type(8))) short short8;   // 8 bf16 MFMA frag
typedef __attribute__((ext_vector_type(4))) float f32x4;
typedef __attribute__((ext_vector_type(2))) float f32x2;

#define C2LOG2E 2.885390081777927f   // 2*log2(e), folded into W1/W2/b1/b2
#define PI_F    3.14159265358979f
#define PIO2_F  1.57079632679490f

__device__ __forceinline__ float rcp_fast(float x) { return __builtin_amdgcn_rcpf(x); }

// Packed pair of tanh sharing ONE rcp; returns bf16x2 as int.
// Arithmetic on float2 ext-vectors -> v_pk_add/mul/fma_f32; final convert via
// v_cvt_pk_bf16_f32 (__float22bfloat162_rn). s pre-scaled by 2*log2(e), bias
// folded into MFMA C-init. Safe: e+1 <= 2^35, product <= 2^70 < fp32 max.
__device__ __forceinline__ int tanh_pair_pk(float s0, float s1) {
    f32x2 e;
    e.x = __builtin_amdgcn_exp2f(s0);
    e.y = __builtin_amdgcn_exp2f(s1);
    f32x2 f = e + 1.0f;                       // v_pk_add_f32
    float r  = rcp_fast(f.x * f.y);
    f32x2 g;
    g.x = f.y; g.y = f.x;                     // op_sel-swappable
    f32x2 t = g * (-2.0f * r) + 1.0f;         // v_pk_fma_f32 (scale folded)
    float2 hv; hv.x = t.x; hv.y = t.y;
    __hip_bfloat162 b = __float22bfloat162_rn(hv);
    return *(int*)&b;
}

__device__ __forceinline__ short bf16_rne(float f) {
    unsigned int u = __float_as_uint(f);
    return (short)((u + 0x7fffu + ((u >> 16) & 1u)) >> 16);
}
// pack two floats as bf16x2 via v_cvt_pk_bf16_f32
__device__ __forceinline__ int bf16pk2(float a, float b) {
    float2 v; v.x = a; v.y = b;
    __hip_bfloat162 t = __float22bfloat162_rn(v);
    return *(int*)&t;
}
__device__ __forceinline__ int bperm_i(int idx_bytes, int v) {
    return __builtin_amdgcn_ds_bpermute(idx_bytes, v);
}

// bf16-accuracy branch-free acos (A&S 4.4.45, |err| < 2e-4 rad)
__device__ __forceinline__ float acos_fast(float w) {
    float a = fabsf(w);
    float s = sqrtf(1.0f - a);
    float p = fmaf(a, fmaf(a, fmaf(a, -0.0187293f, 0.0742610f), -0.2121144f), 1.5707288f);
    float v = s * p;
    return (w >= 0.0f) ? v : PI_F - v;
}
// bf16-accuracy branch-free atan2 (A&S 4.4.49 poly, |err| ~1e-5)
__device__ __forceinline__ float atan2_fast(float y, float x) {
    float ax = fabsf(x), ay = fabsf(y);
    float mx = fmaxf(ax, ay), mn = fminf(ax, ay);
    float t  = mn * rcp_fast(mx);
    float s  = t * t;
    float p  = fmaf(s, fmaf(s, fmaf(s, fmaf(s, 0.0208351f, -0.0851330f),
                                       0.1801410f), -0.3302995f), 0.9998660f);
    float rr = p * t;
    rr = (ay > ax)   ? PIO2_F - rr : rr;
    rr = (x < 0.0f)  ? PI_F  - rr : rr;
    return __builtin_copysignf(rr, y);
}

// launch_bounds(.,4): (.,6) caused scratch spill of weight frags (R7:
// WRITE_SIZE 11.7->149 MB). 4 is the proven no-spill config.
__global__ __launch_bounds__(BLOCK, 4) void
learn_forces_kernel(const float* __restrict__ D_V, const float* __restrict__ logm,
                    const float* __restrict__ W1, const float* __restrict__ b1,
                    const float* __restrict__ W2, const float* __restrict__ b2,
                    const float* __restrict__ W3, const float* __restrict__ b3,
                    const int* __restrict__ senders, const int* __restrict__ receivers,
                    float* __restrict__ out, int ntime)
{
    __shared__ float einv[NP];
    __shared__ int   stab[NP * 9];            // signed edge list per planet: +-(e+1)
    __shared__ int   mpair[NE];               // packed bf16 (lo=lm_recv, hi=lm_send)
    __shared__ float secart[3][EPB];          // SoA cartesian edge forces (8.64 KB)

    const int tid  = threadIdx.x;
    const int wv   = tid >> 6, lane = tid & 63;
    const int m    = lane & 15, q = lane >> 4;

    if (tid < NP) {
        float l = fminf(12.0f, fmaxf(-12.0f, logm[tid]));
        einv[tid] = __expf(-l);
    }
    if (tid < NE) {
        float lr = fminf(12.0f, fmaxf(-12.0f, logm[receivers[tid]]));
        float ls = fminf(12.0f, fmaxf(-12.0f, logm[senders[tid]]));
        mpair[tid] = bf16pk2(lr, ls);
    }
    if (tid < NP) {                           // signed edge table (9 per planet)
        int cnt = 0;
        for (int e = 0; e < NE; ++e) {
            if (receivers[e] == tid) stab[tid * 9 + cnt++] =  (e + 1);
            if (senders[e]   == tid) stab[tid * 9 + cnt++] = -(e + 1);
        }
        for (; cnt < 9; ++cnt) stab[tid * 9 + cnt] = 0;
    }

    // ---- M-permuted weight fragments (invariant: lane's C-regs == next B-frag)
    const int nm = 8 * (m >> 2) + (m & 3);   // + 4t below
    short8 a1[2], a2[2], a3;
    f32x4  cb1[2], cb2[2], cb3;
    #pragma unroll
    for (int t = 0; t < 2; ++t) {
        const int n = nm + 4 * t;
        #pragma unroll
        for (int j = 0; j < 8; ++j) {
            int k = 8 * q + j;
            a1[t][j] = (k < 5) ? bf16_rne(W1[k * 32 + n] * C2LOG2E) : (short)0;
            a2[t][j] = bf16_rne(W2[k * 32 + n] * C2LOG2E);
        }
        #pragma unroll
        for (int r = 0; r < 4; ++r) {
            int nn = 8 * q + 4 * t + r;
            cb1[t][r] = b1[nn] * C2LOG2E;
            cb2[t][r] = b2[nn] * C2LOG2E;
        }
    }
    // L3 with W3 columns replicated across row-quads: A3[row][k] = W3[k][row&3]
    // => every lane's d3[g] regs 0..2 hold (e0,e1,e2) of edge 16g+m directly.
    {
        const int c3 = m & 3;
        #pragma unroll
        for (int j = 0; j < 8; ++j)
            a3[j] = (c3 < 3) ? bf16_rne(W3[(8 * q + j) * 3 + c3]) : (short)0;
        #pragma unroll
        for (int r = 0; r < 4; ++r)
            cb3[r] = (r < 3) ? b3[r] : 0.0f;
    }

    const int bpm = m * 4;                   // bperm idx base: source lane (g<<4)|m
    __syncthreads();

    // software prefetch of first chunk's D_V
    const long ebase = (long)blockIdx.x * EPB;
    float xn = 1.f, yn = 0.f, zn = 0.f;
    {
        int e0i = wv * 64 + lane;
        if (e0i < EPB) {
            const float* dv = D_V + (ebase + e0i) * 3;
            xn = dv[0]; yn = dv[1]; zn = dv[2];
        }
    }

    for (int c = wv; c < NCHUNK; c += 4) {
        const int  e_loc  = c * 64 + lane;
        const bool active = e_loc < EPB;

        float x = xn, y = yn, z = zn;
        // prefetch next chunk
        xn = 1.f; yn = 0.f; zn = 0.f;
        {
            int enx = (c + 4) * 64 + lane;
            if (c + 4 < NCHUNK && enx < EPB) {
                const float* dv = D_V + (ebase + enx) * 3;
                xn = dv[0]; yn = dv[1]; zn = dv[2];
            }
        }

        // ---- own-edge features: one rsqrt serves both r and z/r ----------
        const int le = e_loc % NE;
        float ss  = fmaf(x, x, fmaf(y, y, z * z));
        float rsq = __builtin_amdgcn_rsqf(ss);
        float r   = ss * rsq;
        float zr  = fminf(1.0f, fmaxf(-1.0f, z * rsq));
        float th  = acos_fast(zr);
        float ph  = atan2_fast(y, x);

        // pack features as bf16 pairs BEFORE transport (3 ints carry 5 features)
        int mp   = mpair[le];                              // lo=lmr, hi=lms
        int p_rt = bf16pk2(r, th);                         // k0,k1 (v_cvt_pk)
        int p_pm = (int)__builtin_amdgcn_perm(             // lo=ph (k2), hi=lmr (k3)
                       (unsigned)mp, __float_as_uint(ph) + 0x8000u, 0x05040302u);
        int p_s0 = ((unsigned)mp) >> 16;                   // lo=lms (k4), hi=0

        // ---- S1: 12 bperms move all 4 groups' B-rows (one latency hop) ---
        int b0[4], b1g[4], b2g[4];
        #pragma unroll
        for (int g = 0; g < 4; ++g) {
            const int idx = bpm + g * 64;
            b0[g]  = bperm_i(idx, p_rt);
            b1g[g] = bperm_i(idx, p_pm);
            b2g[g] = bperm_i(idx, p_s0);
        }

        // ---- S2: L1 MFMAs (A zeros at k>=5 mask garbage B rows) ----------
        f32x4 d0[4], d1[4];
        #pragma unroll
        for (int g = 0; g < 4; ++g) {
            short8 bf1;
            int* bi = (int*)&bf1;
            bi[0] = b0[g]; bi[1] = b1g[g]; bi[2] = b2g[g]; bi[3] = 0;
            d0[g] = __builtin_amdgcn_mfma_f32_16x16x32_bf16(a1[0], bf1, cb1[0], 0, 0, 0);
            d1[g] = __builtin_amdgcn_mfma_f32_16x16x32_bf16(a1[1], bf1, cb1[1], 0, 0, 0);
        }

        // ---- S3: packed tanh + L2 MFMAs ----------------------------------
        #pragma unroll
        for (int g = 0; g < 4; ++g) {
            short8 bh;
            int* hb = (int*)&bh;
            hb[0] = tanh_pair_pk(d0[g][0], d0[g][1]);
            hb[1] = tanh_pair_pk(d0[g][2], d0[g][3]);
            hb[2] = tanh_pair_pk(d1[g][0], d1[g][1]);
            hb[3] = tanh_pair_pk(d1[g][2], d1[g][3]);
            d0[g] = __builtin_amdgcn_mfma_f32_16x16x32_bf16(a2[0], bh, cb2[0], 0, 0, 0);
            d1[g] = __builtin_amdgcn_mfma_f32_16x16x32_bf16(a2[1], bh, cb2[1], 0, 0, 0);
        }

        // ---- S4: packed tanh + L3 MFMAs ----------------------------------
        f32x4 d3[4];
        #pragma unroll
        for (int g = 0; g < 4; ++g) {
            short8 bh;
            int* hb = (int*)&bh;
            hb[0] = tanh_pair_pk(d0[g][0], d0[g][1]);
            hb[1] = tanh_pair_pk(d0[g][2], d0[g][3]);
            hb[2] = tanh_pair_pk(d1[g][0], d1[g][1]);
            hb[3] = tanh_pair_pk(d1[g][2], d1[g][3]);
            d3[g] = __builtin_amdgcn_mfma_f32_16x16x32_bf16(a3, bh, cb3, 0, 0, 0);
        }

        // ---- S5: own-group register select (no transport needed) ---------
        float e0a = (q & 1) ? d3[1][0] : d3[0][0], e0b = (q & 1) ? d3[3][0] : d3[2][0];
        float e1a = (q & 1) ? d3[1][1] : d3[0][1], e1b = (q & 1) ? d3[3][1] : d3[2][1];
        float e2a = (q & 1) ? d3[1][2] : d3[0][2], e2b = (q & 1) ? d3[3][2] : d3[2][2];
        float e0 = (q & 2) ? e0b : e0a;
        float e1 = (q & 2) ? e1b : e1a;
        float e2 = (q & 2) ? e2b : e2a;

        // ---- sph -> cart (packed where possible), plain SoA LDS store ----
        float st = __sinf(e1), ct = __cosf(e1);
        float sp = __sinf(e2), cp = __cosf(e2);
        float a  = e0 * st;
        f32x2 xy;
        {
            f32x2 cs; cs.x = cp; cs.y = sp;
            xy = cs * a;                       // v_pk_mul_f32
        }
        if (active) {
            secart[0][e_loc] = xy.x;
            secart[1][e_loc] = xy.y;
            secart[2][e_loc] = e0 * ct;
        }
    }
    __syncthreads();

    // ---- table-driven signed gather-sum: one (t, planet, comp) per thread
    const long t0g = (long)blockIdx.x * TS;
    for (int i = tid; i < TS * NP * 3; i += BLOCK) {
        int t  = i / (NP * 3);
        int pc = i - t * (NP * 3);
        int p  = pc / 3;
        int cc = pc - p * 3;
        const float* row = &secart[cc][t * NE];
        float s = 0.0f;
        #pragma unroll
        for (int j = 0; j < 9; ++j) {
            int es = stab[p * 9 + j];
            int e  = (es < 0 ? -es : es) - 1;
            float v = row[e];
            s += (es > 0) ? v : -v;
        }
        out[t0g * NP * 3 + i] = s * einv[p];   // contiguous 480-float range
    }
}

extern "C" void kernel_launch(void* const* d_in, const int* in_sizes, int n_in,
                              void* d_out, int out_size, void* d_ws, size_t ws_size,
                              hipStream_t stream) {
    const float* D_V  = (const float*)d_in[0];
    const float* logm = (const float*)d_in[1];
    const float* W1   = (const float*)d_in[2];
    const float* b1   = (const float*)d_in[3];
    const float* W2   = (const float*)d_in[4];
    const float* b2   = (const float*)d_in[5];
    const float* W3   = (const float*)d_in[6];
    const float* b3   = (const float*)d_in[7];
    const int* senders   = (const int*)d_in[8];
    const int* receivers = (const int*)d_in[9];

    int nedges = in_sizes[8];               // 45
    int ntime  = in_sizes[0] / 3 / nedges;  // 100000

    int nblocks = (ntime + TS - 1) / TS;    // 6250
    learn_forces_kernel<<<nblocks, BLOCK, 0, stream>>>(
        D_V, logm, W1, b1, W2, b2, W3, b3, senders, receivers,
        (float*)d_out, ntime);
}

// Round 11
// 203.695 us; speedup vs baseline: 1.0084x; 1.0084x over previous
//
#include <hip/hip_runtime.h>
#include <hip/hip_bf16.h>
#include <math.h>

#define NP 10
#define NE 45
#define TS 16                      // timesteps per block
#define EPB (TS * NE)              // 720 edges per block
#define BLOCK 256
#define NCHUNK ((EPB + 63) / 64)   // 12 chunks of 64 edge-slots

typedef __attribute__((ext_vector_type(8)))  short short8;   // 8 bf16 MFMA frag
typedef __attribute__((ext_vector_type(16))) float f32x16;   // 32x32 MFMA acc
typedef __attribute__((ext_vector_type(2)))  float f32x2;

#define C2LOG2E 2.885390081777927f   // 2*log2(e), folded into W1/W2 (+biases)
#define PI_F    3.14159265358979f
#define PIO2_F  1.57079632679490f

#define MFMA32(a, b, c) __builtin_amdgcn_mfma_f32_32x32x16_bf16(a, b, c, 0, 0, 0)

__device__ __forceinline__ float rcp_fast(float x) { return __builtin_amdgcn_rcpf(x); }

// Packed pair of tanh sharing ONE rcp; returns bf16x2 as int.
__device__ __forceinline__ int tanh_pair_pk(float s0, float s1) {
    f32x2 e;
    e.x = __builtin_amdgcn_exp2f(s0);
    e.y = __builtin_amdgcn_exp2f(s1);
    f32x2 f = e + 1.0f;                       // v_pk_add_f32
    float r  = rcp_fast(f.x * f.y);
    f32x2 g;
    g.x = f.y; g.y = f.x;
    f32x2 t = g * (-2.0f * r) + 1.0f;         // v_pk_fma_f32
    float2 hv; hv.x = t.x; hv.y = t.y;
    __hip_bfloat162 b = __float22bfloat162_rn(hv);
    return *(int*)&b;
}

__device__ __forceinline__ short bf16_rne(float f) {
    unsigned int u = __float_as_uint(f);
    return (short)((u + 0x7fffu + ((u >> 16) & 1u)) >> 16);
}
__device__ __forceinline__ int bf16pk2(float a, float b) {
    float2 v; v.x = a; v.y = b;
    __hip_bfloat162 t = __float22bfloat162_rn(v);
    return *(int*)&t;
}
__device__ __forceinline__ int bperm_i(int idx_bytes, int v) {
    return __builtin_amdgcn_ds_bpermute(idx_bytes, v);
}

// bf16-accuracy branch-free acos (A&S 4.4.45)
__device__ __forceinline__ float acos_fast(float w) {
    float a = fabsf(w);
    float s = sqrtf(1.0f - a);
    float p = fmaf(a, fmaf(a, fmaf(a, -0.0187293f, 0.0742610f), -0.2121144f), 1.5707288f);
    float v = s * p;
    return (w >= 0.0f) ? v : PI_F - v;
}
// bf16-accuracy branch-free atan2 (A&S 4.4.49)
__device__ __forceinline__ float atan2_fast(float y, float x) {
    float ax = fabsf(x), ay = fabsf(y);
    float mx = fmaxf(ax, ay), mn = fminf(ax, ay);
    float t  = mn * rcp_fast(mx);
    float s  = t * t;
    float p  = fmaf(s, fmaf(s, fmaf(s, fmaf(s, 0.0208351f, -0.0851330f),
                                       0.1801410f), -0.3302995f), 0.9998660f);
    float rr = p * t;
    rr = (ay > ax)   ? PIO2_F - rr : rr;
    rr = (x < 0.0f)  ? PI_F  - rr : rr;
    return __builtin_copysignf(rr, y);
}

// launch_bounds(.,4): (.,6) spilled weight frags to scratch (R7). Keep 4.
__global__ __launch_bounds__(BLOCK, 4) void
learn_forces_kernel(const float* __restrict__ D_V, const float* __restrict__ logm,
                    const float* __restrict__ W1, const float* __restrict__ b1,
                    const float* __restrict__ W2, const float* __restrict__ b2,
                    const float* __restrict__ W3, const float* __restrict__ b3,
                    const int* __restrict__ senders, const int* __restrict__ receivers,
                    float* __restrict__ out, int ntime)
{
    __shared__ float einv[NP];
    __shared__ int   stab[NP * 9];            // signed edge list per planet: +-(e+1)
    __shared__ int   mpair[NE];               // packed bf16 (lo=lm_recv, hi=lm_send)
    __shared__ float secart[3][EPB];          // SoA cartesian edge forces (8.64 KB)

    const int tid  = threadIdx.x;
    const int wv   = tid >> 6, lane = tid & 63;
    const int n    = lane & 31, h = lane >> 5;

    if (tid < NP) {
        float l = fminf(12.0f, fmaxf(-12.0f, logm[tid]));
        einv[tid] = __expf(-l);
    }
    if (tid < NE) {
        float lr = fminf(12.0f, fmaxf(-12.0f, logm[receivers[tid]]));
        float ls = fminf(12.0f, fmaxf(-12.0f, logm[senders[tid]]));
        mpair[tid] = bf16pk2(lr, ls);
    }
    if (tid < NP) {                           // signed edge table (9 per planet)
        int cnt = 0;
        for (int e = 0; e < NE; ++e) {
            if (receivers[e] == tid) stab[tid * 9 + cnt++] =  (e + 1);
            if (senders[e]   == tid) stab[tid * 9 + cnt++] = -(e + 1);
        }
        for (; cnt < 9; ++cnt) stab[tid * 9 + cnt] = 0;
    }

    // ---- sigma-permuted weights for 32x32x16 register chaining ----------
    // C/D layout: col=lane&31, row=(reg&3)+8*(reg>>2)+4*(lane>>5).
    // Output-neuron nu placed at row sigma(nu) s.t. lane (h,n)'s C-regs 0..7
    // hold neurons 8h..8h+7 of edge n (= B-frag of next layer's k=0..15 MFMA)
    // and regs 8..15 hold neurons 16+8h..16+8h+7 (k=16..31 MFMA).
    // Row n holds neuron nu(n):
    const int nu = 16 * (n >> 4) + 8 * ((n >> 2) & 1) + 4 * ((n >> 3) & 1) + (n & 3);
    const int c3 = n & 3;                     // L3: replicated output component

    short8 a1, a2a, a2b, a3a, a3b;
    f32x16 cb2, zf16;
    #pragma unroll
    for (int j = 0; j < 8; ++j) {
        const int k = 8 * h + j;
        float w1v = 0.0f;                     // L1: k=0..4 features, k=5 bias-one
        if (h == 0) {
            if (j < 5)       w1v = W1[j * 32 + nu] * C2LOG2E;
            else if (j == 5) w1v = b1[nu] * C2LOG2E;
        }
        a1[j]  = bf16_rne(w1v);
        a2a[j] = bf16_rne(W2[k * 32 + nu] * C2LOG2E);
        a2b[j] = bf16_rne(W2[(16 + k) * 32 + nu] * C2LOG2E);
        a3a[j] = (c3 < 3) ? bf16_rne(W3[k * 3 + c3]) : (short)0;
        a3b[j] = (c3 < 3) ? bf16_rne(W3[(16 + k) * 3 + c3]) : (short)0;
    }
    #pragma unroll
    for (int r = 0; r < 16; ++r) {
        int neuron = (r < 8) ? (8 * h + r) : (16 + 8 * h + (r - 8));
        cb2[r]  = b2[neuron] * C2LOG2E;
        zf16[r] = 0.0f;
    }
    const float b30 = b3[0], b31 = b3[1], b32 = b3[2];

    const int idxg1 = (n | 32) * 4;          // group-1 source lane (32+n)
    __syncthreads();

    // software prefetch of first chunk's D_V
    const long ebase = (long)blockIdx.x * EPB;
    float xn = 1.f, yn = 0.f, zn = 0.f;
    {
        int e0i = wv * 64 + lane;
        if (e0i < EPB) {
            const float* dv = D_V + (ebase + e0i) * 3;
            xn = dv[0]; yn = dv[1]; zn = dv[2];
        }
    }

    for (int c = wv; c < NCHUNK; c += 4) {
        const int  e_loc  = c * 64 + lane;
        const bool active = e_loc < EPB;

        float x = xn, y = yn, z = zn;
        // prefetch next chunk
        xn = 1.f; yn = 0.f; zn = 0.f;
        {
            int enx = (c + 4) * 64 + lane;
            if (c + 4 < NCHUNK && enx < EPB) {
                const float* dv = D_V + (ebase + enx) * 3;
                xn = dv[0]; yn = dv[1]; zn = dv[2];
            }
        }

        // ---- own-edge features ------------------------------------------
        const int le = e_loc % NE;
        float ss  = fmaf(x, x, fmaf(y, y, z * z));
        float rsq = __builtin_amdgcn_rsqf(ss);
        float r   = ss * rsq;
        float zr  = fminf(1.0f, fmaxf(-1.0f, z * rsq));
        float th  = acos_fast(zr);
        float ph  = atan2_fast(y, x);

        int mp   = mpair[le];                              // lo=lmr, hi=lms
        int p_rt = bf16pk2(r, th);                         // k0,k1
        int p_pm = (int)__builtin_amdgcn_perm(             // lo=ph (k2), hi=lmr (k3)
                       (unsigned)mp, __float_as_uint(ph) + 0x8000u, 0x05040302u);
        int p_s1 = (int)(((unsigned)mp >> 16) | 0x3F800000u); // k4=lms, k5=1.0 (bias)

        // ---- group-1 transport: 3 bperms (group 0 is lane-local) --------
        int q_rt = bperm_i(idxg1, p_rt);
        int q_pm = bperm_i(idxg1, p_pm);
        int q_s1 = bperm_i(idxg1, p_s1);

        // B-frags: h=1 lanes carry garbage at k=8..15 — masked by A1==0 there
        short8 bf0, bf1;
        { int* b = (int*)&bf0; b[0] = p_rt; b[1] = p_pm; b[2] = p_s1; b[3] = 0; }
        { int* b = (int*)&bf1; b[0] = q_rt; b[1] = q_pm; b[2] = q_s1; b[3] = 0; }

        // ---- L1: one MFMA per 32-edge group -----------------------------
        f32x16 dA = MFMA32(a1, bf0, zf16);
        f32x16 dB = MFMA32(a1, bf1, zf16);

        // ---- L1 tanh -> L2 (2 chained MFMAs per group) ------------------
        short8 hA0, hA1, hB0, hB1;
        {
            int* p = (int*)&hA0; int* q2 = (int*)&hA1;
            p[0]  = tanh_pair_pk(dA[0],  dA[1]);  p[1]  = tanh_pair_pk(dA[2],  dA[3]);
            p[2]  = tanh_pair_pk(dA[4],  dA[5]);  p[3]  = tanh_pair_pk(dA[6],  dA[7]);
            q2[0] = tanh_pair_pk(dA[8],  dA[9]);  q2[1] = tanh_pair_pk(dA[10], dA[11]);
            q2[2] = tanh_pair_pk(dA[12], dA[13]); q2[3] = tanh_pair_pk(dA[14], dA[15]);
        }
        {
            int* p = (int*)&hB0; int* q2 = (int*)&hB1;
            p[0]  = tanh_pair_pk(dB[0],  dB[1]);  p[1]  = tanh_pair_pk(dB[2],  dB[3]);
            p[2]  = tanh_pair_pk(dB[4],  dB[5]);  p[3]  = tanh_pair_pk(dB[6],  dB[7]);
            q2[0] = tanh_pair_pk(dB[8],  dB[9]);  q2[1] = tanh_pair_pk(dB[10], dB[11]);
            q2[2] = tanh_pair_pk(dB[12], dB[13]); q2[3] = tanh_pair_pk(dB[14], dB[15]);
        }
        f32x16 eA = MFMA32(a2a, hA0, cb2);
        eA        = MFMA32(a2b, hA1, eA);
        f32x16 eB = MFMA32(a2a, hB0, cb2);
        eB        = MFMA32(a2b, hB1, eB);

        // ---- L2 tanh -> L3 (2 chained MFMAs per group) ------------------
        {
            int* p = (int*)&hA0; int* q2 = (int*)&hA1;
            p[0]  = tanh_pair_pk(eA[0],  eA[1]);  p[1]  = tanh_pair_pk(eA[2],  eA[3]);
            p[2]  = tanh_pair_pk(eA[4],  eA[5]);  p[3]  = tanh_pair_pk(eA[6],  eA[7]);
            q2[0] = tanh_pair_pk(eA[8],  eA[9]);  q2[1] = tanh_pair_pk(eA[10], eA[11]);
            q2[2] = tanh_pair_pk(eA[12], eA[13]); q2[3] = tanh_pair_pk(eA[14], eA[15]);
        }
        {
            int* p = (int*)&hB0; int* q2 = (int*)&hB1;
            p[0]  = tanh_pair_pk(eB[0],  eB[1]);  p[1]  = tanh_pair_pk(eB[2],  eB[3]);
            p[2]  = tanh_pair_pk(eB[4],  eB[5]);  p[3]  = tanh_pair_pk(eB[6],  eB[7]);
            q2[0] = tanh_pair_pk(eB[8],  eB[9]);  q2[1] = tanh_pair_pk(eB[10], eB[11]);
            q2[2] = tanh_pair_pk(eB[12], eB[13]); q2[3] = tanh_pair_pk(eB[14], eB[15]);
        }
        f32x16 oA = MFMA32(a3a, hA0, zf16);
        oA        = MFMA32(a3b, hA1, oA);
        f32x16 oB = MFMA32(a3a, hB0, zf16);
        oB        = MFMA32(a3b, hB1, oB);

        // ---- own edge = group h, column n: regs 0..2 = (e0,e1,e2) -------
        float e0 = (h ? oB[0] : oA[0]) + b30;
        float e1 = (h ? oB[1] : oA[1]) + b31;
        float e2 = (h ? oB[2] : oA[2]) + b32;

        // ---- sph -> cart, plain SoA LDS store ---------------------------
        float st = __sinf(e1), ct = __cosf(e1);
        float sp = __sinf(e2), cp = __cosf(e2);
        float am = e0 * st;
        f32x2 xy;
        {
            f32x2 cs; cs.x = cp; cs.y = sp;
            xy = cs * am;                      // v_pk_mul_f32
        }
        if (active) {
            secart[0][e_loc] = xy.x;
            secart[1][e_loc] = xy.y;
            secart[2][e_loc] = e0 * ct;
        }
    }
    __syncthreads();

    // ---- table-driven signed gather-sum: one (t, planet, comp) per thread
    const long t0g = (long)blockIdx.x * TS;
    for (int i = tid; i < TS * NP * 3; i += BLOCK) {
        int t  = i / (NP * 3);
        int pc = i - t * (NP * 3);
        int p  = pc / 3;
        int cc = pc - p * 3;
        const float* row = &secart[cc][t * NE];
        float s = 0.0f;
        #pragma unroll
        for (int j = 0; j < 9; ++j) {
            int es = stab[p * 9 + j];
            int e  = (es < 0 ? -es : es) - 1;
            float v = row[e];
            s += (es > 0) ? v : -v;
        }
        out[t0g * NP * 3 + i] = s * einv[p];   // contiguous 480-float range
    }
}

extern "C" void kernel_launch(void* const* d_in, const int* in_sizes, int n_in,
                              void* d_out, int out_size, void* d_ws, size_t ws_size,
                              hipStream_t stream) {
    const float* D_V  = (const float*)d_in[0];
    const float* logm = (const float*)d_in[1];
    const float* W1   = (const float*)d_in[2];
    const float* b1   = (const float*)d_in[3];
    const float* W2   = (const float*)d_in[4];
    const float* b2   = (const float*)d_in[5];
    const float* W3   = (const float*)d_in[6];
    const float* b3   = (const float*)d_in[7];
    const int* senders   = (const int*)d_in[8];
    const int* receivers = (const int*)d_in[9];

    int nedges = in_sizes[8];               // 45
    int ntime  = in_sizes[0] / 3 / nedges;  // 100000

    int nblocks = (ntime + TS - 1) / TS;    // 6250
    learn_forces_kernel<<<nblocks, BLOCK, 0, stream>>>(
        D_V, logm, W1, b1, W2, b2, W3, b3, senders, receivers,
        (float*)d_out, ntime);
}